// Round 4
// baseline (100.604 us; speedup 1.0000x reference)
//
#include <hip/hip_runtime.h>

#define BATCH 4
#define LQ    10000
#define DM    256
#define NH    8
#define NP    4
#define HWD   100
#define LIN   10000

typedef unsigned short ushort_t;
typedef __attribute__((ext_vector_type(8))) short bf16x8;
typedef __attribute__((ext_vector_type(8))) unsigned short u16x8;
typedef __attribute__((ext_vector_type(4))) float f32x4;

__device__ __forceinline__ unsigned short f2bf(float f) {
    unsigned int u = __float_as_uint(f);
    u += 0x7FFFu + ((u >> 16) & 1u);          // round-to-nearest-even
    return (unsigned short)(u >> 16);
}

// ---------------------------------------------------------------------------
// Prep: WtV/WtO = bf16(W^T) 256x256; Wcomb[96][256] = bf16([Woff|Wa]^T);
// bcomb[96] = [boff|ba]. grid (256,3) x 256 threads.
// ---------------------------------------------------------------------------
__global__ __launch_bounds__(256) void prep_kernel(
    const float* __restrict__ Wv, const float* __restrict__ Wout,
    const float* __restrict__ Woff, const float* __restrict__ Wa,
    const float* __restrict__ boff, const float* __restrict__ ba,
    ushort_t* __restrict__ WtV, ushort_t* __restrict__ WtO,
    ushort_t* __restrict__ Wcomb, float* __restrict__ bcomb)
{
    const int n = blockIdx.x, k = threadIdx.x;
    if (blockIdx.y == 0) {
        WtV[n * 256 + k] = f2bf(Wv[(size_t)k * 256 + n]);
    } else if (blockIdx.y == 1) {
        WtO[n * 256 + k] = f2bf(Wout[(size_t)k * 256 + n]);
    } else if (n < 96) {
        float w = (n < 64) ? Woff[(size_t)k * 64 + n] : Wa[(size_t)k * 32 + (n - 64)];
        Wcomb[n * 256 + k] = f2bf(w);
        if (k == 0) bcomb[n] = (n < 64) ? boff[n] : ba[n - 64];
    }
}

// ---------------------------------------------------------------------------
// MFMA GEMM: C[M][256] = A[M][256] @ W + bias. Wt = W^T bf16 [n][k].
// BM=64, BN=256, BK=32; 4 waves, wave w owns cols w*64..+63 (4x4 frags).
// ---------------------------------------------------------------------------
template<bool IN_BF16, bool OUT_BF16>
__global__ __launch_bounds__(256) void gemm_mfma_kernel(
    const void* __restrict__ Ain, const ushort_t* __restrict__ Wt,
    const float* __restrict__ bias, void* __restrict__ Cout)
{
    __shared__ ushort_t As[64 * 32];
    __shared__ ushort_t Bs[256 * 32];

    const int tid  = threadIdx.x;
    const int lane = tid & 63;
    const int wv   = tid >> 6;
    const int row0 = blockIdx.x * 64;

    const f32x4 zero = {0.f, 0.f, 0.f, 0.f};
    f32x4 acc[4][4];
    #pragma unroll
    for (int m = 0; m < 4; ++m)
        #pragma unroll
        for (int n = 0; n < 4; ++n) acc[m][n] = zero;

    const int ar  = tid >> 2;
    const int akb = tid & 3;
    const int asw = (akb ^ ((ar >> 1) & 3)) * 8;
    const int fr = lane & 15, kb = lane >> 4;

    for (int k0 = 0; k0 < 256; k0 += 32) {
        if (IN_BF16) {
            const ushort_t* A = (const ushort_t*)Ain;
            uint4 v = *reinterpret_cast<const uint4*>(
                &A[(size_t)(row0 + ar) * 256 + k0 + akb * 8]);
            *reinterpret_cast<uint4*>(&As[ar * 32 + asw]) = v;
        } else {
            const float* A = (const float*)Ain;
            const float* p = &A[(size_t)(row0 + ar) * 256 + k0 + akb * 8];
            float4 f0 = *reinterpret_cast<const float4*>(p);
            float4 f1 = *reinterpret_cast<const float4*>(p + 4);
            u16x8 pk;
            pk[0] = f2bf(f0.x); pk[1] = f2bf(f0.y);
            pk[2] = f2bf(f0.z); pk[3] = f2bf(f0.w);
            pk[4] = f2bf(f1.x); pk[5] = f2bf(f1.y);
            pk[6] = f2bf(f1.z); pk[7] = f2bf(f1.w);
            *reinterpret_cast<u16x8*>(&As[ar * 32 + asw]) = pk;
        }
        #pragma unroll
        for (int j = 0; j < 4; ++j) {
            int n = (tid >> 2) + 64 * j;
            uint4 v = *reinterpret_cast<const uint4*>(
                &Wt[(size_t)n * 256 + k0 + akb * 8]);
            *reinterpret_cast<uint4*>(
                &Bs[n * 32 + ((akb ^ ((n >> 1) & 3)) * 8)]) = v;
        }
        __syncthreads();

        bf16x8 af[4], bf[4];
        #pragma unroll
        for (int m = 0; m < 4; ++m) {
            int r = m * 16 + fr;
            af[m] = *reinterpret_cast<const bf16x8*>(
                &As[r * 32 + ((kb ^ ((r >> 1) & 3)) * 8)]);
        }
        #pragma unroll
        for (int n = 0; n < 4; ++n) {
            int c = wv * 64 + n * 16 + fr;
            bf[n] = *reinterpret_cast<const bf16x8*>(
                &Bs[c * 32 + ((kb ^ ((c >> 1) & 3)) * 8)]);
        }
        #pragma unroll
        for (int m = 0; m < 4; ++m)
            #pragma unroll
            for (int n = 0; n < 4; ++n)
                acc[m][n] = __builtin_amdgcn_mfma_f32_16x16x32_bf16(
                    af[m], bf[n], acc[m][n], 0, 0, 0);
        __syncthreads();
    }

    #pragma unroll
    for (int m = 0; m < 4; ++m) {
        #pragma unroll
        for (int n = 0; n < 4; ++n) {
            int c = wv * 64 + n * 16 + fr;
            float bb = bias[c];
            #pragma unroll
            for (int j = 0; j < 4; ++j) {
                int r = row0 + m * 16 + kb * 4 + j;
                float v = acc[m][n][j] + bb;
                if (OUT_BF16)
                    ((ushort_t*)Cout)[(size_t)r * 256 + c] = f2bf(v);
                else
                    ((float*)Cout)[(size_t)r * 256 + c] = v;
            }
        }
    }
}

// ---------------------------------------------------------------------------
// Projection GEMM: oaproj[M][96] = query[M][256] @ Wcomb^T + bcomb (f32 out).
// ---------------------------------------------------------------------------
__global__ __launch_bounds__(256) void gemm_proj_kernel(
    const float* __restrict__ A, const ushort_t* __restrict__ Wt,
    const float* __restrict__ bias, float* __restrict__ C)
{
    __shared__ ushort_t As[64 * 32];
    __shared__ ushort_t Bs[96 * 32];

    const int tid  = threadIdx.x;
    const int lane = tid & 63;
    const int wv   = tid >> 6;
    const int row0 = blockIdx.x * 64;

    const f32x4 zero = {0.f, 0.f, 0.f, 0.f};
    f32x4 acc[6];
    #pragma unroll
    for (int n = 0; n < 6; ++n) acc[n] = zero;

    const int ar  = tid >> 2;
    const int akb = tid & 3;
    const int asw = (akb ^ ((ar >> 1) & 3)) * 8;
    const int fr = lane & 15, kb = lane >> 4;

    for (int k0 = 0; k0 < 256; k0 += 32) {
        {
            const float* p = &A[(size_t)(row0 + ar) * 256 + k0 + akb * 8];
            float4 f0 = *reinterpret_cast<const float4*>(p);
            float4 f1 = *reinterpret_cast<const float4*>(p + 4);
            u16x8 pk;
            pk[0] = f2bf(f0.x); pk[1] = f2bf(f0.y);
            pk[2] = f2bf(f0.z); pk[3] = f2bf(f0.w);
            pk[4] = f2bf(f1.x); pk[5] = f2bf(f1.y);
            pk[6] = f2bf(f1.z); pk[7] = f2bf(f1.w);
            *reinterpret_cast<u16x8*>(&As[ar * 32 + asw]) = pk;
        }
        #pragma unroll
        for (int j = 0; j < 2; ++j) {
            int n = (tid >> 2) + 64 * j;
            if (n < 96) {
                uint4 v = *reinterpret_cast<const uint4*>(
                    &Wt[(size_t)n * 256 + k0 + akb * 8]);
                *reinterpret_cast<uint4*>(
                    &Bs[n * 32 + ((akb ^ ((n >> 1) & 3)) * 8)]) = v;
            }
        }
        __syncthreads();

        bf16x8 af;
        {
            int r = wv * 16 + fr;
            af = *reinterpret_cast<const bf16x8*>(
                &As[r * 32 + ((kb ^ ((r >> 1) & 3)) * 8)]);
        }
        #pragma unroll
        for (int n = 0; n < 6; ++n) {
            int c = n * 16 + fr;
            bf16x8 bf = *reinterpret_cast<const bf16x8*>(
                &Bs[c * 32 + ((kb ^ ((c >> 1) & 3)) * 8)]);
            acc[n] = __builtin_amdgcn_mfma_f32_16x16x32_bf16(
                af, bf, acc[n], 0, 0, 0);
        }
        __syncthreads();
    }

    #pragma unroll
    for (int n = 0; n < 6; ++n) {
        int c = n * 16 + fr;
        float bb = bias[c];
        #pragma unroll
        for (int j = 0; j < 4; ++j) {
            int r = row0 + wv * 16 + kb * 4 + j;
            C[(size_t)r * 96 + c] = acc[n][j] + bb;
        }
    }
}

// ---------------------------------------------------------------------------
// Fused deform + output GEMM. Block = 64 global rows (grid 625, no tail).
// Phase 1 (x4 groups of 16 q): coords -> register-batched gather (16 uint4
// in flight) -> bf16 accumulate into LDS tile At[64][256] (XOR-swizzled).
// Phase 2: out[64][256] = At @ WtO^T + bout via MFMA, Bs unions coords LDS.
// ---------------------------------------------------------------------------
__global__ __launch_bounds__(256) void fused_deform_out_kernel(
    const float* __restrict__ oaproj, const float* __restrict__ refpts,
    const ushort_t* __restrict__ value, const ushort_t* __restrict__ WtO,
    const float* __restrict__ bias, float* __restrict__ out)
{
    __shared__ ushort_t At[64 * 256];            // 32 KB bf16 ws2 tile
    __shared__ __align__(16) char shu[16384];    // union: coords | Bs

    int4*     soff = reinterpret_cast<int4*>(shu);            // [NP][128]
    float4*   swt  = reinterpret_cast<float4*>(shu + 8192);   // [NP][128]
    ushort_t* Bs   = reinterpret_cast<ushort_t*>(shu);        // [256*32]

    const int tid  = threadIdx.x;
    const int wv   = tid >> 6;
    const int lane = tid & 63;
    const int r0   = blockIdx.x * 64;

    const int c8 = lane & 3, s = lane >> 2;
    const int h_g = s & 7, qpair = s >> 3;
    const int chan = h_g * 32 + c8 * 8;

    for (int g = 0; g < 4; ++g) {
        // ---- coords for 16 queries (threads 0..127: ql=tid>>3, h=tid&7) ----
        if (tid < 128) {
            const int ql = tid >> 3, h = tid & 7;
            const size_t row = (size_t)(r0 + g * 16 + ql);
            const float* oa = oaproj + row * 96;
            float4 l4 = *reinterpret_cast<const float4*>(oa + 64 + h * 4);
            float mx = fmaxf(fmaxf(l4.x, l4.y), fmaxf(l4.z, l4.w));
            float e0 = __expf(l4.x - mx), e1 = __expf(l4.y - mx);
            float e2 = __expf(l4.z - mx), e3 = __expf(l4.w - mx);
            float inv = 1.f / (e0 + e1 + e2 + e3);
            float ew[4] = {e0 * inv, e1 * inv, e2 * inv, e3 * inv};
            float4 o0 = *reinterpret_cast<const float4*>(oa + h * 8);
            float4 o1 = *reinterpret_cast<const float4*>(oa + h * 8 + 4);
            float oxv[4] = {o0.x, o0.z, o1.x, o1.z};
            float oyv[4] = {o0.y, o0.w, o1.y, o1.w};
            const float* rp = refpts + row * 4;
            float cx = rp[0], cy = rp[1], rw = rp[2], rh = rp[3];
            #pragma unroll
            for (int p = 0; p < NP; ++p) {
                float x = (cx + oxv[p] * rw * 0.125f) * (float)HWD - 0.5f;
                float y = (cy + oyv[p] * rh * 0.125f) * (float)HWD - 0.5f;
                float x0f = floorf(x), y0f = floorf(y);
                float wx = x - x0f, wy = y - y0f;
                int x0 = (int)x0f, y0 = (int)y0f;
                int x1 = x0 + 1, y1 = y0 + 1;
                float vx0 = (x0 >= 0 && x0 < HWD) ? 1.f : 0.f;
                float vx1 = (x1 >= 0 && x1 < HWD) ? 1.f : 0.f;
                float vy0 = (y0 >= 0 && y0 < HWD) ? 1.f : 0.f;
                float vy1 = (y1 >= 0 && y1 < HWD) ? 1.f : 0.f;
                int cx0 = min(max(x0, 0), HWD - 1), cx1 = min(max(x1, 0), HWD - 1);
                int cy0 = min(max(y0, 0), HWD - 1), cy1 = min(max(y1, 0), HWD - 1);
                float aw = ew[p];
                int4 of = {cy0 * HWD + cx0, cy0 * HWD + cx1,
                           cy1 * HWD + cx0, cy1 * HWD + cx1};
                float4 wt = {aw * (1.f - wx) * (1.f - wy) * vx0 * vy0,
                             aw * wx * (1.f - wy) * vx1 * vy0,
                             aw * (1.f - wx) * wy * vx0 * vy1,
                             aw * wx * wy * vx1 * vy1};
                soff[p * 128 + tid] = of;
                swt [p * 128 + tid] = wt;
            }
        }
        __syncthreads();

        // ---- gather: 2 passes, 16 uint4 preloaded per pass ----
        #pragma unroll
        for (int pass = 0; pass < 2; ++pass) {
            const int ql  = wv * 4 + pass * 2 + qpair;   // 0..15
            const int row = g * 16 + ql;                 // tile row 0..63
            const int r   = r0 + row;
            const int b   = (int)((unsigned)r / 10000u);
            const ushort_t* vb = value + (size_t)b * (LIN * 256) + chan;
            const int qh = ql * 8 + h_g;

            int4 of[4]; float4 w4[4];
            #pragma unroll
            for (int p = 0; p < NP; ++p) {
                of[p] = soff[p * 128 + qh];
                w4[p] = swt [p * 128 + qh];
            }
            uint4 vv[4][4];
            #pragma unroll
            for (int p = 0; p < NP; ++p) {
                vv[p][0] = *reinterpret_cast<const uint4*>(vb + ((size_t)of[p].x << 8));
                vv[p][1] = *reinterpret_cast<const uint4*>(vb + ((size_t)of[p].y << 8));
                vv[p][2] = *reinterpret_cast<const uint4*>(vb + ((size_t)of[p].z << 8));
                vv[p][3] = *reinterpret_cast<const uint4*>(vb + ((size_t)of[p].w << 8));
            }
            float a0 = 0.f, a1 = 0.f, a2 = 0.f, a3 = 0.f;
            float a4 = 0.f, a5 = 0.f, a6 = 0.f, a7 = 0.f;
            #define ACC(V, W) { const float w_ = (W); const uint4 v_ = (V); \
                a0 += w_ * __uint_as_float(v_.x << 16); \
                a1 += w_ * __uint_as_float(v_.x & 0xffff0000u); \
                a2 += w_ * __uint_as_float(v_.y << 16); \
                a3 += w_ * __uint_as_float(v_.y & 0xffff0000u); \
                a4 += w_ * __uint_as_float(v_.z << 16); \
                a5 += w_ * __uint_as_float(v_.z & 0xffff0000u); \
                a6 += w_ * __uint_as_float(v_.w << 16); \
                a7 += w_ * __uint_as_float(v_.w & 0xffff0000u); }
            #pragma unroll
            for (int p = 0; p < NP; ++p) {
                ACC(vv[p][0], w4[p].x);
                ACC(vv[p][1], w4[p].y);
                ACC(vv[p][2], w4[p].z);
                ACC(vv[p][3], w4[p].w);
            }
            #undef ACC
            u16x8 pk;
            pk[0] = f2bf(a0); pk[1] = f2bf(a1);
            pk[2] = f2bf(a2); pk[3] = f2bf(a3);
            pk[4] = f2bf(a4); pk[5] = f2bf(a5);
            pk[6] = f2bf(a6); pk[7] = f2bf(a7);
            const int chunk = h_g * 4 + c8;                      // 0..31
            const int mem = (chunk & 24) | ((chunk ^ row) & 7);  // XOR swizzle
            *reinterpret_cast<u16x8*>(&At[row * 256 + mem * 8]) = pk;
        }
        __syncthreads();
    }

    // ---- phase 2: out = At @ WtO^T + bias (f32) ----
    const f32x4 zero = {0.f, 0.f, 0.f, 0.f};
    f32x4 acc[4][4];
    #pragma unroll
    for (int m = 0; m < 4; ++m)
        #pragma unroll
        for (int n = 0; n < 4; ++n) acc[m][n] = zero;

    const int fr = lane & 15, kb = lane >> 4;
    const int akb = tid & 3;

    for (int k0 = 0; k0 < 256; k0 += 32) {
        #pragma unroll
        for (int j = 0; j < 4; ++j) {
            int n = (tid >> 2) + 64 * j;
            uint4 v = *reinterpret_cast<const uint4*>(
                &WtO[(size_t)n * 256 + k0 + akb * 8]);
            *reinterpret_cast<uint4*>(
                &Bs[n * 32 + ((akb ^ ((n >> 1) & 3)) * 8)]) = v;
        }
        __syncthreads();

        bf16x8 af[4], bf[4];
        #pragma unroll
        for (int m = 0; m < 4; ++m) {
            int row = m * 16 + fr;
            int chunk = (k0 >> 3) + kb;
            int mem = (chunk & 24) | ((chunk ^ row) & 7);
            af[m] = *reinterpret_cast<const bf16x8*>(&At[row * 256 + mem * 8]);
        }
        #pragma unroll
        for (int n = 0; n < 4; ++n) {
            int c = wv * 64 + n * 16 + fr;
            bf[n] = *reinterpret_cast<const bf16x8*>(
                &Bs[c * 32 + ((kb ^ ((c >> 1) & 3)) * 8)]);
        }
        #pragma unroll
        for (int m = 0; m < 4; ++m)
            #pragma unroll
            for (int n = 0; n < 4; ++n)
                acc[m][n] = __builtin_amdgcn_mfma_f32_16x16x32_bf16(
                    af[m], bf[n], acc[m][n], 0, 0, 0);
        __syncthreads();
    }

    #pragma unroll
    for (int m = 0; m < 4; ++m) {
        #pragma unroll
        for (int n = 0; n < 4; ++n) {
            int c = wv * 64 + n * 16 + fr;
            float bb = bias[c];
            #pragma unroll
            for (int j = 0; j < 4; ++j) {
                int r = r0 + m * 16 + kb * 4 + j;
                out[(size_t)r * 256 + c] = acc[m][n][j] + bb;
            }
        }
    }
}

// ---------------------------------------------------------------------------
extern "C" void kernel_launch(void* const* d_in, const int* in_sizes, int n_in,
                              void* d_out, int out_size, void* d_ws, size_t ws_size,
                              hipStream_t stream)
{
    const float* query  = (const float*)d_in[0];
    const float* refpts = (const float*)d_in[1];
    const float* flat   = (const float*)d_in[2];
    const float* Wv   = (const float*)d_in[6];
    const float* bv   = (const float*)d_in[7];
    const float* Woff = (const float*)d_in[8];
    const float* boff = (const float*)d_in[9];
    const float* Wa   = (const float*)d_in[10];
    const float* ba   = (const float*)d_in[11];
    const float* Wout = (const float*)d_in[12];
    const float* bout = (const float*)d_in[13];
    float* out = (float*)d_out;

    const size_t MROWS = (size_t)BATCH * LIN;            // 40000
    ushort_t* value  = (ushort_t*)d_ws;                  // 40000x256 bf16
    ushort_t* WtV    = value + MROWS * DM;               // 256x256 bf16
    ushort_t* WtO    = WtV + 256 * 256;                  // 256x256 bf16
    ushort_t* Wcomb  = WtO + 256 * 256;                  // 96x256 bf16
    float*    bcomb  = (float*)(Wcomb + 96 * 256);       // 96 f32 (+pad)
    float*    oaproj = bcomb + 128;                      // 40000x96 f32

    dim3 blk(256);

    prep_kernel<<<dim3(256, 3), blk, 0, stream>>>(
        Wv, Wout, Woff, Wa, boff, ba, WtV, WtO, Wcomb, bcomb);

    gemm_mfma_kernel<false, true><<<dim3(MROWS / 64), blk, 0, stream>>>(
        flat, WtV, bv, value);

    gemm_proj_kernel<<<dim3(MROWS / 64), blk, 0, stream>>>(
        query, Wcomb, bcomb, oaproj);

    fused_deform_out_kernel<<<dim3(MROWS / 64), blk, 0, stream>>>(
        oaproj, refpts, value, WtO, bout, out);
}

// Round 5
// 90.275 us; speedup vs baseline: 1.1144x; 1.1144x over previous
//
#include <hip/hip_runtime.h>

#define BATCH 4
#define LQ    10000
#define DM    256
#define NH    8
#define NP    4
#define HWD   100
#define LIN   10000

typedef unsigned short ushort_t;
typedef __attribute__((ext_vector_type(8))) short bf16x8;
typedef __attribute__((ext_vector_type(8))) unsigned short u16x8;
typedef __attribute__((ext_vector_type(4))) float f32x4;

__device__ __forceinline__ unsigned short f2bf(float f) {
    unsigned int u = __float_as_uint(f);
    u += 0x7FFFu + ((u >> 16) & 1u);          // round-to-nearest-even
    return (unsigned short)(u >> 16);
}

// ---------------------------------------------------------------------------
// Prep: WtV/WtO = bf16(W^T) 256x256; Wcomb[96][256] = bf16([Woff|Wa]^T);
// bcomb[96] = [boff|ba]. grid (256,3) x 256 threads.
// ---------------------------------------------------------------------------
__global__ __launch_bounds__(256) void prep_kernel(
    const float* __restrict__ Wv, const float* __restrict__ Wout,
    const float* __restrict__ Woff, const float* __restrict__ Wa,
    const float* __restrict__ boff, const float* __restrict__ ba,
    ushort_t* __restrict__ WtV, ushort_t* __restrict__ WtO,
    ushort_t* __restrict__ Wcomb, float* __restrict__ bcomb)
{
    const int n = blockIdx.x, k = threadIdx.x;
    if (blockIdx.y == 0) {
        WtV[n * 256 + k] = f2bf(Wv[(size_t)k * 256 + n]);
    } else if (blockIdx.y == 1) {
        WtO[n * 256 + k] = f2bf(Wout[(size_t)k * 256 + n]);
    } else if (n < 96) {
        float w = (n < 64) ? Woff[(size_t)k * 64 + n] : Wa[(size_t)k * 32 + (n - 64)];
        Wcomb[n * 256 + k] = f2bf(w);
        if (k == 0) bcomb[n] = (n < 64) ? boff[n] : ba[n - 64];
    }
}

// ---------------------------------------------------------------------------
// MFMA GEMM: C[M][256] = A[M][256] @ W + bias. Wt = W^T bf16 [n][k].
// BM=64, BN=256, BK=32; 4 waves, wave w owns cols w*64..+63 (4x4 frags).
// ---------------------------------------------------------------------------
template<bool IN_BF16, bool OUT_BF16>
__global__ __launch_bounds__(256) void gemm_mfma_kernel(
    const void* __restrict__ Ain, const ushort_t* __restrict__ Wt,
    const float* __restrict__ bias, void* __restrict__ Cout)
{
    __shared__ ushort_t As[64 * 32];
    __shared__ ushort_t Bs[256 * 32];

    const int tid  = threadIdx.x;
    const int lane = tid & 63;
    const int wv   = tid >> 6;
    const int row0 = blockIdx.x * 64;

    const f32x4 zero = {0.f, 0.f, 0.f, 0.f};
    f32x4 acc[4][4];
    #pragma unroll
    for (int m = 0; m < 4; ++m)
        #pragma unroll
        for (int n = 0; n < 4; ++n) acc[m][n] = zero;

    const int ar  = tid >> 2;
    const int akb = tid & 3;
    const int asw = (akb ^ ((ar >> 1) & 3)) * 8;
    const int fr = lane & 15, kb = lane >> 4;

    for (int k0 = 0; k0 < 256; k0 += 32) {
        if (IN_BF16) {
            const ushort_t* A = (const ushort_t*)Ain;
            uint4 v = *reinterpret_cast<const uint4*>(
                &A[(size_t)(row0 + ar) * 256 + k0 + akb * 8]);
            *reinterpret_cast<uint4*>(&As[ar * 32 + asw]) = v;
        } else {
            const float* A = (const float*)Ain;
            const float* p = &A[(size_t)(row0 + ar) * 256 + k0 + akb * 8];
            float4 f0 = *reinterpret_cast<const float4*>(p);
            float4 f1 = *reinterpret_cast<const float4*>(p + 4);
            u16x8 pk;
            pk[0] = f2bf(f0.x); pk[1] = f2bf(f0.y);
            pk[2] = f2bf(f0.z); pk[3] = f2bf(f0.w);
            pk[4] = f2bf(f1.x); pk[5] = f2bf(f1.y);
            pk[6] = f2bf(f1.z); pk[7] = f2bf(f1.w);
            *reinterpret_cast<u16x8*>(&As[ar * 32 + asw]) = pk;
        }
        #pragma unroll
        for (int j = 0; j < 4; ++j) {
            int n = (tid >> 2) + 64 * j;
            uint4 v = *reinterpret_cast<const uint4*>(
                &Wt[(size_t)n * 256 + k0 + akb * 8]);
            *reinterpret_cast<uint4*>(
                &Bs[n * 32 + ((akb ^ ((n >> 1) & 3)) * 8)]) = v;
        }
        __syncthreads();

        bf16x8 af[4], bf[4];
        #pragma unroll
        for (int m = 0; m < 4; ++m) {
            int r = m * 16 + fr;
            af[m] = *reinterpret_cast<const bf16x8*>(
                &As[r * 32 + ((kb ^ ((r >> 1) & 3)) * 8)]);
        }
        #pragma unroll
        for (int n = 0; n < 4; ++n) {
            int c = wv * 64 + n * 16 + fr;
            bf[n] = *reinterpret_cast<const bf16x8*>(
                &Bs[c * 32 + ((kb ^ ((c >> 1) & 3)) * 8)]);
        }
        #pragma unroll
        for (int m = 0; m < 4; ++m)
            #pragma unroll
            for (int n = 0; n < 4; ++n)
                acc[m][n] = __builtin_amdgcn_mfma_f32_16x16x32_bf16(
                    af[m], bf[n], acc[m][n], 0, 0, 0);
        __syncthreads();
    }

    #pragma unroll
    for (int m = 0; m < 4; ++m) {
        #pragma unroll
        for (int n = 0; n < 4; ++n) {
            int c = wv * 64 + n * 16 + fr;
            float bb = bias[c];
            #pragma unroll
            for (int j = 0; j < 4; ++j) {
                int r = row0 + m * 16 + kb * 4 + j;
                float v = acc[m][n][j] + bb;
                if (OUT_BF16)
                    ((ushort_t*)Cout)[(size_t)r * 256 + c] = f2bf(v);
                else
                    ((float*)Cout)[(size_t)r * 256 + c] = v;
            }
        }
    }
}

// ---------------------------------------------------------------------------
// Projection GEMM: oaproj[M][96] = query[M][256] @ Wcomb^T + bcomb (f32 out).
// ---------------------------------------------------------------------------
__global__ __launch_bounds__(256) void gemm_proj_kernel(
    const float* __restrict__ A, const ushort_t* __restrict__ Wt,
    const float* __restrict__ bias, float* __restrict__ C)
{
    __shared__ ushort_t As[64 * 32];
    __shared__ ushort_t Bs[96 * 32];

    const int tid  = threadIdx.x;
    const int lane = tid & 63;
    const int wv   = tid >> 6;
    const int row0 = blockIdx.x * 64;

    const f32x4 zero = {0.f, 0.f, 0.f, 0.f};
    f32x4 acc[6];
    #pragma unroll
    for (int n = 0; n < 6; ++n) acc[n] = zero;

    const int ar  = tid >> 2;
    const int akb = tid & 3;
    const int asw = (akb ^ ((ar >> 1) & 3)) * 8;
    const int fr = lane & 15, kb = lane >> 4;

    for (int k0 = 0; k0 < 256; k0 += 32) {
        {
            const float* p = &A[(size_t)(row0 + ar) * 256 + k0 + akb * 8];
            float4 f0 = *reinterpret_cast<const float4*>(p);
            float4 f1 = *reinterpret_cast<const float4*>(p + 4);
            u16x8 pk;
            pk[0] = f2bf(f0.x); pk[1] = f2bf(f0.y);
            pk[2] = f2bf(f0.z); pk[3] = f2bf(f0.w);
            pk[4] = f2bf(f1.x); pk[5] = f2bf(f1.y);
            pk[6] = f2bf(f1.z); pk[7] = f2bf(f1.w);
            *reinterpret_cast<u16x8*>(&As[ar * 32 + asw]) = pk;
        }
        #pragma unroll
        for (int j = 0; j < 2; ++j) {
            int n = (tid >> 2) + 64 * j;
            if (n < 96) {
                uint4 v = *reinterpret_cast<const uint4*>(
                    &Wt[(size_t)n * 256 + k0 + akb * 8]);
                *reinterpret_cast<uint4*>(
                    &Bs[n * 32 + ((akb ^ ((n >> 1) & 3)) * 8)]) = v;
            }
        }
        __syncthreads();

        bf16x8 af;
        {
            int r = wv * 16 + fr;
            af = *reinterpret_cast<const bf16x8*>(
                &As[r * 32 + ((kb ^ ((r >> 1) & 3)) * 8)]);
        }
        #pragma unroll
        for (int n = 0; n < 6; ++n) {
            int c = n * 16 + fr;
            bf16x8 bf = *reinterpret_cast<const bf16x8*>(
                &Bs[c * 32 + ((kb ^ ((c >> 1) & 3)) * 8)]);
            acc[n] = __builtin_amdgcn_mfma_f32_16x16x32_bf16(
                af, bf, acc[n], 0, 0, 0);
        }
        __syncthreads();
    }

    #pragma unroll
    for (int n = 0; n < 6; ++n) {
        int c = n * 16 + fr;
        float bb = bias[c];
        #pragma unroll
        for (int j = 0; j < 4; ++j) {
            int r = row0 + wv * 16 + kb * 4 + j;
            C[(size_t)r * 96 + c] = acc[n][j] + bb;
        }
    }
}

// ---------------------------------------------------------------------------
// Deform: oaproj -> softmax/coords (LDS) -> register-batched wide gathers ->
// ws2 bf16. Block = 16 queries of ONE batch, 256 threads.
// XCD-affinity swizzle: grid 2504 = 313*8; xcd = blk&7 (dispatch round-robin
// heuristic), batch b = xcd>>1  ->  each XCD's 4 MB L2 only sees one batch's
// 5.1 MB value slab instead of all 20.5 MB.
// ---------------------------------------------------------------------------
__global__ __launch_bounds__(256) void deform_kernel(
    const float* __restrict__ oaproj, const float* __restrict__ refpts,
    const ushort_t* __restrict__ value, ushort_t* __restrict__ out)
{
    __shared__ int4   soff[NP * 128];   // [p][q*8+h] clamped y*100+x (4 corners)
    __shared__ float4 swt [NP * 128];   // [p][q*8+h] attn*bilerp*valid

    const int blk = blockIdx.x;
    const int xcd = blk & 7;
    const int b = xcd >> 1;
    const int qchunk = (blk >> 3) * 2 + (xcd & 1);
    if (qchunk >= LQ / 16) return;      // uniform over the block
    const int q0 = qchunk * 16;

    const int tid = threadIdx.x;

    if (tid < 128) {
        const int ql = tid >> 3, h = tid & 7;
        const size_t row = (size_t)(b * LQ + q0 + ql);
        const float* oa = oaproj + row * 96;
        float4 l4 = *reinterpret_cast<const float4*>(oa + 64 + h * 4);
        float mx = fmaxf(fmaxf(l4.x, l4.y), fmaxf(l4.z, l4.w));
        float e0 = __expf(l4.x - mx), e1 = __expf(l4.y - mx);
        float e2 = __expf(l4.z - mx), e3 = __expf(l4.w - mx);
        float inv = 1.f / (e0 + e1 + e2 + e3);
        float ew[4] = {e0 * inv, e1 * inv, e2 * inv, e3 * inv};
        float4 o0 = *reinterpret_cast<const float4*>(oa + h * 8);
        float4 o1 = *reinterpret_cast<const float4*>(oa + h * 8 + 4);
        float oxv[4] = {o0.x, o0.z, o1.x, o1.z};
        float oyv[4] = {o0.y, o0.w, o1.y, o1.w};
        const float* rp = refpts + row * 4;
        float cx = rp[0], cy = rp[1], rw = rp[2], rh = rp[3];
        #pragma unroll
        for (int p = 0; p < NP; ++p) {
            float x = (cx + oxv[p] * rw * 0.125f) * (float)HWD - 0.5f;
            float y = (cy + oyv[p] * rh * 0.125f) * (float)HWD - 0.5f;
            float x0f = floorf(x), y0f = floorf(y);
            float wx = x - x0f, wy = y - y0f;
            int x0 = (int)x0f, y0 = (int)y0f;
            int x1 = x0 + 1, y1 = y0 + 1;
            float vx0 = (x0 >= 0 && x0 < HWD) ? 1.f : 0.f;
            float vx1 = (x1 >= 0 && x1 < HWD) ? 1.f : 0.f;
            float vy0 = (y0 >= 0 && y0 < HWD) ? 1.f : 0.f;
            float vy1 = (y1 >= 0 && y1 < HWD) ? 1.f : 0.f;
            int cx0 = min(max(x0, 0), HWD - 1), cx1 = min(max(x1, 0), HWD - 1);
            int cy0 = min(max(y0, 0), HWD - 1), cy1 = min(max(y1, 0), HWD - 1);
            float aw = ew[p];
            int4 of = {cy0 * HWD + cx0, cy0 * HWD + cx1,
                       cy1 * HWD + cx0, cy1 * HWD + cx1};
            float4 wt = {aw * (1.f - wx) * (1.f - wy) * vx0 * vy0,
                         aw * wx * (1.f - wy) * vx1 * vy0,
                         aw * (1.f - wx) * wy * vx0 * vy1,
                         aw * wx * wy * vx1 * vy1};
            soff[p * 128 + tid] = of;
            swt [p * 128 + tid] = wt;
        }
    }
    __syncthreads();

    const int wv = tid >> 6, lane = tid & 63;
    const int c8 = lane & 3, s = lane >> 2;
    const int h_g = s & 7, qpair = s >> 3;
    const int chan = h_g * 32 + c8 * 8;
    const ushort_t* vb = value + (size_t)b * (LIN * 256) + chan;

    #pragma unroll
    for (int pass = 0; pass < 2; ++pass) {
        const int q = wv * 4 + pass * 2 + qpair;   // 0..15
        const int qh = q * 8 + h_g;

        int4 of[4]; float4 w4[4];
        #pragma unroll
        for (int p = 0; p < NP; ++p) {
            of[p] = soff[p * 128 + qh];
            w4[p] = swt [p * 128 + qh];
        }
        // 16 independent loads in flight, then accumulate
        uint4 vv[4][4];
        #pragma unroll
        for (int p = 0; p < NP; ++p) {
            vv[p][0] = *reinterpret_cast<const uint4*>(vb + ((size_t)of[p].x << 8));
            vv[p][1] = *reinterpret_cast<const uint4*>(vb + ((size_t)of[p].y << 8));
            vv[p][2] = *reinterpret_cast<const uint4*>(vb + ((size_t)of[p].z << 8));
            vv[p][3] = *reinterpret_cast<const uint4*>(vb + ((size_t)of[p].w << 8));
        }
        float a0 = 0.f, a1 = 0.f, a2 = 0.f, a3 = 0.f;
        float a4 = 0.f, a5 = 0.f, a6 = 0.f, a7 = 0.f;
        #define ACC(V, W) { const float w_ = (W); const uint4 v_ = (V); \
            a0 += w_ * __uint_as_float(v_.x << 16); \
            a1 += w_ * __uint_as_float(v_.x & 0xffff0000u); \
            a2 += w_ * __uint_as_float(v_.y << 16); \
            a3 += w_ * __uint_as_float(v_.y & 0xffff0000u); \
            a4 += w_ * __uint_as_float(v_.z << 16); \
            a5 += w_ * __uint_as_float(v_.z & 0xffff0000u); \
            a6 += w_ * __uint_as_float(v_.w << 16); \
            a7 += w_ * __uint_as_float(v_.w & 0xffff0000u); }
        #pragma unroll
        for (int p = 0; p < NP; ++p) {
            ACC(vv[p][0], w4[p].x);
            ACC(vv[p][1], w4[p].y);
            ACC(vv[p][2], w4[p].z);
            ACC(vv[p][3], w4[p].w);
        }
        #undef ACC

        const size_t orow = (size_t)(b * LQ + q0 + q);
        u16x8 pk;
        pk[0] = f2bf(a0); pk[1] = f2bf(a1);
        pk[2] = f2bf(a2); pk[3] = f2bf(a3);
        pk[4] = f2bf(a4); pk[5] = f2bf(a5);
        pk[6] = f2bf(a6); pk[7] = f2bf(a7);
        *reinterpret_cast<u16x8*>(&out[orow * 256 + chan]) = pk;
    }
}

// ---------------------------------------------------------------------------
extern "C" void kernel_launch(void* const* d_in, const int* in_sizes, int n_in,
                              void* d_out, int out_size, void* d_ws, size_t ws_size,
                              hipStream_t stream)
{
    const float* query  = (const float*)d_in[0];
    const float* refpts = (const float*)d_in[1];
    const float* flat   = (const float*)d_in[2];
    const float* Wv   = (const float*)d_in[6];
    const float* bv   = (const float*)d_in[7];
    const float* Woff = (const float*)d_in[8];
    const float* boff = (const float*)d_in[9];
    const float* Wa   = (const float*)d_in[10];
    const float* ba   = (const float*)d_in[11];
    const float* Wout = (const float*)d_in[12];
    const float* bout = (const float*)d_in[13];
    float* out = (float*)d_out;

    const size_t MROWS = (size_t)BATCH * LIN;            // 40000
    ushort_t* value  = (ushort_t*)d_ws;                  // 40000x256 bf16
    ushort_t* ws2    = value + MROWS * DM;               // 40000x256 bf16
    ushort_t* WtV    = ws2 + MROWS * DM;                 // 256x256 bf16
    ushort_t* WtO    = WtV + 256 * 256;                  // 256x256 bf16
    ushort_t* Wcomb  = WtO + 256 * 256;                  // 96x256 bf16
    float*    bcomb  = (float*)(Wcomb + 96 * 256);       // 96 f32 (+pad)
    float*    oaproj = bcomb + 128;                      // 40000x96 f32

    dim3 blk(256);

    prep_kernel<<<dim3(256, 3), blk, 0, stream>>>(
        Wv, Wout, Woff, Wa, boff, ba, WtV, WtO, Wcomb, bcomb);

    gemm_mfma_kernel<false, true><<<dim3(MROWS / 64), blk, 0, stream>>>(
        flat, WtV, bv, value);

    gemm_proj_kernel<<<dim3(MROWS / 64), blk, 0, stream>>>(
        query, Wcomb, bcomb, oaproj);

    deform_kernel<<<dim3(313 * 8), blk, 0, stream>>>(
        oaproj, refpts, value, ws2);

    gemm_mfma_kernel<true, false><<<dim3(MROWS / 64), blk, 0, stream>>>(
        ws2, WtO, bout, out);
}